// Round 1
// baseline (450.020 us; speedup 1.0000x reference)
//
#include <hip/hip_runtime.h>
#include <hip/hip_bf16.h>

#define NTOK 65536   // B*S = 64*1024
#define CIN  768
#define NDIM 8
#define NLVL 15

// ---------------------------------------------------------------------------
// Kernel A: zc = z @ Wc^T + bc  (f64), stash zc into first 64B of each out row,
// and accumulate KDE sums (f64) via block-reduce + global f64 atomics.
// One token per wave iteration; lane owns 12 channels (c = 4*lane + 256*m + k).
// ---------------------------------------------------------------------------
__global__ __launch_bounds__(256, 2)
void fsq_compress_kde(const float* __restrict__ z, const float* __restrict__ Wc,
                      const float* __restrict__ bc, const float* __restrict__ centers,
                      float* out, double* __restrict__ kde_sum)
{
    const int lane  = threadIdx.x & 63;
    const int gwave = blockIdx.x * 4 + (threadIdx.x >> 6);   // 0..2047

    // Wc -> f64 registers: Wcd[d][m*4+k] for channel c = 4*lane + 256*m + k
    double Wcd[NDIM][12];
#pragma unroll
    for (int d = 0; d < NDIM; ++d) {
#pragma unroll
        for (int m = 0; m < 3; ++m) {
            const float4 w4 = *(const float4*)(Wc + d * CIN + m * 256 + lane * 4);
            Wcd[d][m * 4 + 0] = (double)w4.x;
            Wcd[d][m * 4 + 1] = (double)w4.y;
            Wcd[d][m * 4 + 2] = (double)w4.z;
            Wcd[d][m * 4 + 3] = (double)w4.w;
        }
    }
    double bcd[NDIM];
#pragma unroll
    for (int d = 0; d < NDIM; ++d) bcd[d] = (double)bc[d];

    // KDE pair assignment: lane -> (d0, lA) and optionally (d0, lA+8)
    const int    d0   = lane >> 3;
    const int    lA   = lane & 7;
    const bool   hasB = (lA < 7);                       // levels 8..14
    const double cA   = (double)centers[d0 * NLVL + lA];
    const double cB   = hasB ? (double)centers[d0 * NLVL + lA + 8] : 0.0;
    double kAcc = 0.0, kBcc = 0.0;

    for (int t = 0; t < 32; ++t) {
        const int    n  = gwave * 32 + t;
        const float* zp = z + (size_t)n * CIN;
        const float4 a0 = *(const float4*)(zp + lane * 4);
        const float4 a1 = *(const float4*)(zp + 256 + lane * 4);
        const float4 a2 = *(const float4*)(zp + 512 + lane * 4);

        double acc[NDIM];
#pragma unroll
        for (int d = 0; d < NDIM; ++d) acc[d] = 0.0;

        {
            const double x0 = (double)a0.x, x1 = (double)a0.y, x2 = (double)a0.z, x3 = (double)a0.w;
#pragma unroll
            for (int d = 0; d < NDIM; ++d) {
                acc[d] = fma(x0, Wcd[d][0], acc[d]);
                acc[d] = fma(x1, Wcd[d][1], acc[d]);
                acc[d] = fma(x2, Wcd[d][2], acc[d]);
                acc[d] = fma(x3, Wcd[d][3], acc[d]);
            }
        }
        {
            const double x0 = (double)a1.x, x1 = (double)a1.y, x2 = (double)a1.z, x3 = (double)a1.w;
#pragma unroll
            for (int d = 0; d < NDIM; ++d) {
                acc[d] = fma(x0, Wcd[d][4], acc[d]);
                acc[d] = fma(x1, Wcd[d][5], acc[d]);
                acc[d] = fma(x2, Wcd[d][6], acc[d]);
                acc[d] = fma(x3, Wcd[d][7], acc[d]);
            }
        }
        {
            const double x0 = (double)a2.x, x1 = (double)a2.y, x2 = (double)a2.z, x3 = (double)a2.w;
#pragma unroll
            for (int d = 0; d < NDIM; ++d) {
                acc[d] = fma(x0, Wcd[d][8],  acc[d]);
                acc[d] = fma(x1, Wcd[d][9],  acc[d]);
                acc[d] = fma(x2, Wcd[d][10], acc[d]);
                acc[d] = fma(x3, Wcd[d][11], acc[d]);
            }
        }

        // full-wave butterfly reduction (all lanes end with the full sums)
#pragma unroll
        for (int off = 32; off >= 1; off >>= 1) {
#pragma unroll
            for (int d = 0; d < NDIM; ++d)
                acc[d] += __shfl_xor(acc[d], off, 64);
        }
#pragma unroll
        for (int d = 0; d < NDIM; ++d) acc[d] += bcd[d];

        // stash zc[n][lane] (f64 bits) into first 64B of out row n (lanes 0..7)
        double zst = acc[0];
#pragma unroll
        for (int j = 1; j < NDIM; ++j)
            if ((lane & 7) == j) zst = acc[j];
        if (lane < 8)
            __builtin_memcpy(out + (size_t)n * CIN + 2 * lane, &zst, 8);

        // KDE: lane's dim value
        double zd = acc[0];
#pragma unroll
        for (int j = 1; j < NDIM; ++j)
            if (d0 == j) zd = acc[j];

        const double tA = (cA - zd) * 2.0;           // / BANDWIDTH(0.5)
        kAcc += exp(-0.5 * tA * tA);
        const double tB = (cB - zd) * 2.0;
        const double eB = exp(-0.5 * tB * tB);
        kBcc += hasB ? eB : 0.0;
    }

    // block reduce (4 waves share identical lane->pair mapping), then atomics
    __shared__ double sA[256];
    __shared__ double sB[256];
    sA[threadIdx.x] = kAcc;
    sB[threadIdx.x] = kBcc;
    __syncthreads();
    if (threadIdx.x < 64) {
        const double rA = sA[threadIdx.x] + sA[threadIdx.x + 64] +
                          sA[threadIdx.x + 128] + sA[threadIdx.x + 192];
        const double rB = sB[threadIdx.x] + sB[threadIdx.x + 64] +
                          sB[threadIdx.x + 128] + sB[threadIdx.x + 192];
        const int d = threadIdx.x >> 3, l = threadIdx.x & 7;
        unsafeAtomicAdd(&kde_sum[d * NLVL + l], rA);
        if (l < 7) unsafeAtomicAdd(&kde_sum[d * NLVL + 8 + l], rB);
    }
}

// ---------------------------------------------------------------------------
// Kernel B: scaled = centers * (w / w.sum(axis=1)), w = kde_mean + 1e-6  (f64)
// Also writes the reference tuple's scalar second output (0.0f).
// ---------------------------------------------------------------------------
__global__ void fsq_scale(const double* __restrict__ kde_sum,
                          const float* __restrict__ centers,
                          double* __restrict__ scaled, float* out_scalar)
{
    __shared__ double w[NDIM * NLVL];
    const int t = threadIdx.x;
    if (t < NDIM * NLVL)
        w[t] = kde_sum[t] * (1.0 / 65536.0) + 1e-6;
    __syncthreads();
    if (t < NDIM * NLVL) {
        const int d = t / NLVL;
        double s = 0.0;
#pragma unroll
        for (int l = 0; l < NLVL; ++l) s += w[d * NLVL + l];
        scaled[t] = (double)centers[t] * (w[t] / s);
    }
    if (t == 0) *out_scalar = 0.0f;
}

// ---------------------------------------------------------------------------
// Kernel C: per token, f64 nearest-scaled-center per dim (lane%8 duplicated),
// then fp32 expand z_q = q @ We^T + be. Reads zc from the row head it will
// overwrite (same wave, load-before-store).
// ---------------------------------------------------------------------------
__global__ __launch_bounds__(256, 2)
void fsq_quant_expand(const double* __restrict__ scaled, const float* __restrict__ We,
                      const float* __restrict__ be, float* out)
{
    const int lane  = threadIdx.x & 63;
    const int gwave = blockIdx.x * 4 + (threadIdx.x >> 6);

    float Wer[12][NDIM];
    float ber[12];
#pragma unroll
    for (int m = 0; m < 3; ++m) {
#pragma unroll
        for (int k = 0; k < 4; ++k) {
            const int    c  = lane * 4 + 256 * m + k;
            const float4 u0 = *(const float4*)(We + c * NDIM);
            const float4 u1 = *(const float4*)(We + c * NDIM + 4);
            Wer[m * 4 + k][0] = u0.x; Wer[m * 4 + k][1] = u0.y;
            Wer[m * 4 + k][2] = u0.z; Wer[m * 4 + k][3] = u0.w;
            Wer[m * 4 + k][4] = u1.x; Wer[m * 4 + k][5] = u1.y;
            Wer[m * 4 + k][6] = u1.z; Wer[m * 4 + k][7] = u1.w;
            ber[m * 4 + k] = be[c];
        }
    }

    const int dsel = lane & 7;
    double sc[NLVL];
#pragma unroll
    for (int l = 0; l < NLVL; ++l) sc[l] = scaled[dsel * NLVL + l];

    for (int t = 0; t < 32; ++t) {
        const int n  = gwave * 32 + t;
        float*    op = out + (size_t)n * CIN;

        double zd;
        __builtin_memcpy(&zd, op + 2 * dsel, 8);

        // first-min argmin (matches np.argmin tie-break)
        double best = fabs(zd - sc[0]);
        double q    = sc[0];
#pragma unroll
        for (int l = 1; l < NLVL; ++l) {
            const double dd = fabs(zd - sc[l]);
            if (dd < best) { best = dd; q = sc[l]; }
        }
        const float qf = (float)q;

        float qa[NDIM];
#pragma unroll
        for (int j = 0; j < NDIM; ++j) qa[j] = __shfl(qf, j, 64);

#pragma unroll
        for (int m = 0; m < 3; ++m) {
            float v[4];
#pragma unroll
            for (int k = 0; k < 4; ++k) {
                float s = ber[m * 4 + k];
#pragma unroll
                for (int j = 0; j < NDIM; ++j)
                    s = fmaf(qa[j], Wer[m * 4 + k][j], s);
                v[k] = s;
            }
            *(float4*)(op + m * 256 + lane * 4) = make_float4(v[0], v[1], v[2], v[3]);
        }
    }
}

// ---------------------------------------------------------------------------
extern "C" void kernel_launch(void* const* d_in, const int* in_sizes, int n_in,
                              void* d_out, int out_size, void* d_ws, size_t ws_size,
                              hipStream_t stream)
{
    const float* z       = (const float*)d_in[0];
    const float* Wc      = (const float*)d_in[1];
    const float* bc      = (const float*)d_in[2];
    const float* We      = (const float*)d_in[3];
    const float* be      = (const float*)d_in[4];
    const float* centers = (const float*)d_in[5];
    float*       out     = (float*)d_out;

    double* kde_sum = (double*)d_ws;            // 120 doubles
    double* scaled  = (double*)d_ws + 128;      // 120 doubles @ +1KB

    hipMemsetAsync(kde_sum, 0, NDIM * NLVL * sizeof(double), stream);
    fsq_compress_kde<<<512, 256, 0, stream>>>(z, Wc, bc, centers, out, kde_sum);
    fsq_scale<<<1, 128, 0, stream>>>(kde_sum, centers, scaled,
                                     out + (size_t)out_size - 1);
    fsq_quant_expand<<<512, 256, 0, stream>>>(scaled, We, be, out);
}